// Round 1
// baseline (2533.502 us; speedup 1.0000x reference)
//
#include <hip/hip_runtime.h>

// MPLayer: y[b,v] += p[r]*x[b,u]; y[b,u] += p[r]*x[b,v]  for each edge (u,v) in relation r.
// R=64, E=100000, N=1000000, B=4.

constexpr int  R_ = 64;
constexpr long E_ = 100000;
constexpr int  N_ = 1000000;
constexpr int  B_ = 4;

// --- transpose x [4][N] -> xT [N][4] (float4 per entity) ---
__global__ void k_transpose_x(const float* __restrict__ x, float4* __restrict__ xT) {
    int i = blockIdx.x * blockDim.x + threadIdx.x;
    if (i < N_) {
        float4 v;
        v.x = x[i];
        v.y = x[(long)N_ + i];
        v.z = x[2L * N_ + i];
        v.w = x[3L * N_ + i];
        xT[i] = v;
    }
}

// --- scatter: one directed-pair per edge, atomics into yT [N][4] ---
__global__ void k_scatter_T(const int2* __restrict__ edges, const float* __restrict__ p,
                            const float4* __restrict__ xT, float* __restrict__ yT) {
    const long total  = (long)R_ * E_;
    const long stride = (long)gridDim.x * blockDim.x;
    for (long k = (long)blockIdx.x * blockDim.x + threadIdx.x; k < total; k += stride) {
        int2 e = edges[k];
        float w = p[(int)(k / E_)];
        float4 xu = xT[e.x];
        float4 xv = xT[e.y];
        float* du = &yT[4L * e.x];
        float* dv = &yT[4L * e.y];
        atomicAdd(&dv[0], w * xu.x);
        atomicAdd(&dv[1], w * xu.y);
        atomicAdd(&dv[2], w * xu.z);
        atomicAdd(&dv[3], w * xu.w);
        atomicAdd(&du[0], w * xv.x);
        atomicAdd(&du[1], w * xv.y);
        atomicAdd(&du[2], w * xv.z);
        atomicAdd(&du[3], w * xv.w);
    }
}

// --- transpose yT [N][4] -> y [4][N] ---
__global__ void k_transpose_y(const float4* __restrict__ yT, float* __restrict__ y) {
    int i = blockIdx.x * blockDim.x + threadIdx.x;
    if (i < N_) {
        float4 v = yT[i];
        y[i]            = v.x;
        y[(long)N_ + i] = v.y;
        y[2L * N_ + i]  = v.z;
        y[3L * N_ + i]  = v.w;
    }
}

// --- fallback: direct atomics into y [4][N] if workspace too small ---
__global__ void k_scatter_direct(const int2* __restrict__ edges, const float* __restrict__ p,
                                 const float* __restrict__ x, float* __restrict__ y) {
    const long total  = (long)R_ * E_;
    const long stride = (long)gridDim.x * blockDim.x;
    for (long k = (long)blockIdx.x * blockDim.x + threadIdx.x; k < total; k += stride) {
        int2 e = edges[k];
        float w = p[(int)(k / E_)];
        #pragma unroll
        for (int b = 0; b < B_; ++b) {
            float xu = x[(long)b * N_ + e.x];
            float xv = x[(long)b * N_ + e.y];
            atomicAdd(&y[(long)b * N_ + e.y], w * xu);
            atomicAdd(&y[(long)b * N_ + e.x], w * xv);
        }
    }
}

extern "C" void kernel_launch(void* const* d_in, const int* in_sizes, int n_in,
                              void* d_out, int out_size, void* d_ws, size_t ws_size,
                              hipStream_t stream) {
    const float* p     = (const float*)d_in[0];
    const int*   edges = (const int*)d_in[1];   // int32 per harness contract, values < N
    const float* x     = (const float*)d_in[2];
    float*       y     = (float*)d_out;

    const size_t xT_bytes = (size_t)N_ * 4 * sizeof(float);   // 16 MB
    const size_t yT_bytes = (size_t)N_ * 4 * sizeof(float);   // 16 MB

    if (ws_size >= xT_bytes + yT_bytes) {
        float4* xT = (float4*)d_ws;
        float*  yT = (float*)((char*)d_ws + xT_bytes);
        hipMemsetAsync(yT, 0, yT_bytes, stream);
        k_transpose_x<<<(N_ + 255) / 256, 256, 0, stream>>>(x, xT);
        k_scatter_T<<<4096, 256, 0, stream>>>((const int2*)edges, p, (const float4*)xT, yT);
        k_transpose_y<<<(N_ + 255) / 256, 256, 0, stream>>>((const float4*)xT == nullptr ? nullptr : (const float4*)yT, y);
    } else {
        hipMemsetAsync(y, 0, (size_t)out_size * sizeof(float), stream);
        k_scatter_direct<<<4096, 256, 0, stream>>>((const int2*)edges, p, x, y);
    }
}

// Round 2
// 643.814 us; speedup vs baseline: 3.9351x; 3.9351x over previous
//
#include <hip/hip_runtime.h>

// MPLayer: y[b,v] += p[r]*x[b,u]; y[b,u] += p[r]*x[b,v]  per edge (u,v), relation r.
// R=64, E=100000, N=1000000, B=4.
// Layout trick: xT/yT are [N][4] (float4 per entity). Each directed message m
// is handled by 4 consecutive lanes (one per batch component c) so the gather
// (xT[4s+c]) and the atomic (yT[4d+c]) are each ONE 16B segment per message
// within a single wave instruction -> 4x fewer atomic transactions than
// one-thread-per-edge with 8 scalar atomics.

constexpr int  R_ = 64;
constexpr long E_ = 100000;
constexpr int  N_ = 1000000;
constexpr long RE_ = (long)R_ * E_;     // 6.4M edges
constexpr long M2_ = 2 * RE_;           // 12.8M directed messages

__global__ __launch_bounds__(256) void k_transpose_x(const float* __restrict__ x,
                                                     float4* __restrict__ xT) {
    int i = blockIdx.x * blockDim.x + threadIdx.x;
    if (i < N_) {
        float4 v;
        v.x = x[i];
        v.y = x[(long)N_ + i];
        v.z = x[2L * N_ + i];
        v.w = x[3L * N_ + i];
        xT[i] = v;
    }
}

// one thread per (directed message, batch component)
__global__ __launch_bounds__(256) void k_scatter_T2(const int2* __restrict__ edges,
                                                    const float* __restrict__ p,
                                                    const float* __restrict__ xT,
                                                    float* __restrict__ yT) {
    const long total  = M2_ * 4;              // 51.2M lane-tasks
    const long stride = (long)gridDim.x * blockDim.x;
    for (long t = (long)blockIdx.x * blockDim.x + threadIdx.x; t < total; t += stride) {
        long m = t >> 2;                      // directed message id
        int  c = (int)(t & 3);                // batch component
        long mm = (m >= RE_) ? (m - RE_) : m; // undirected edge id
        int2 e = edges[mm];                   // 4 lanes share this address
        int s, d;
        if (m >= RE_) { s = e.y; d = e.x; } else { s = e.x; d = e.y; }
        float w   = p[(int)(mm / E_)];
        float val = w * xT[4L * s + c];       // 4 lanes -> one 16B segment
        atomicAdd(&yT[4L * d + c], val);      // 4 lanes -> one 16B segment
    }
}

__global__ __launch_bounds__(256) void k_transpose_y(const float4* __restrict__ yT,
                                                     float* __restrict__ y) {
    int i = blockIdx.x * blockDim.x + threadIdx.x;
    if (i < N_) {
        float4 v = yT[i];
        y[i]            = v.x;
        y[(long)N_ + i] = v.y;
        y[2L * N_ + i]  = v.z;
        y[3L * N_ + i]  = v.w;
    }
}

// fallback: direct atomics into y [4][N] if workspace too small
__global__ __launch_bounds__(256) void k_scatter_direct(const int2* __restrict__ edges,
                                                        const float* __restrict__ p,
                                                        const float* __restrict__ x,
                                                        float* __restrict__ y) {
    const long stride = (long)gridDim.x * blockDim.x;
    for (long k = (long)blockIdx.x * blockDim.x + threadIdx.x; k < RE_; k += stride) {
        int2 e = edges[k];
        float w = p[(int)(k / E_)];
        #pragma unroll
        for (int b = 0; b < 4; ++b) {
            float xu = x[(long)b * N_ + e.x];
            float xv = x[(long)b * N_ + e.y];
            atomicAdd(&y[(long)b * N_ + e.y], w * xu);
            atomicAdd(&y[(long)b * N_ + e.x], w * xv);
        }
    }
}

extern "C" void kernel_launch(void* const* d_in, const int* in_sizes, int n_in,
                              void* d_out, int out_size, void* d_ws, size_t ws_size,
                              hipStream_t stream) {
    const float* p     = (const float*)d_in[0];
    const int*   edges = (const int*)d_in[1];
    const float* x     = (const float*)d_in[2];
    float*       y     = (float*)d_out;

    const size_t xT_bytes = (size_t)N_ * 4 * sizeof(float);   // 16 MB
    const size_t yT_bytes = (size_t)N_ * 4 * sizeof(float);   // 16 MB

    if (ws_size >= xT_bytes + yT_bytes) {
        float4* xT = (float4*)d_ws;
        float*  yT = (float*)((char*)d_ws + xT_bytes);
        hipMemsetAsync(yT, 0, yT_bytes, stream);
        k_transpose_x<<<(N_ + 255) / 256, 256, 0, stream>>>(x, xT);
        k_scatter_T2<<<16384, 256, 0, stream>>>((const int2*)edges, p,
                                                (const float*)xT, yT);
        k_transpose_y<<<(N_ + 255) / 256, 256, 0, stream>>>((const float4*)yT, y);
    } else {
        hipMemsetAsync(y, 0, (size_t)out_size * sizeof(float), stream);
        k_scatter_direct<<<8192, 256, 0, stream>>>((const int2*)edges, p, x, y);
    }
}